// Round 3
// baseline (150.303 us; speedup 1.0000x reference)
//
#include <hip/hip_runtime.h>

typedef float f4 __attribute__((ext_vector_type(4)));

#define N 1536
#define D 768
#define H 64
#define NN (N * N)

// ---------------------------------------------------------------------------
// Kernel 1: A[i,h] = (E @ W1a)[i,h] + b1[h] - p_i.Wp[h] - v_i.Wv[h]
//           B[j,h] = (E @ W1b)[j,h]        + p_j.Wp[h] + v_j.Wv[h]
// P[kc][h2][i], h2 in [0,128): 0..63 = A, 64..127 = B.
// 8-row i-tiles, 128 threads (2 waves), 768 blocks -> exactly 3 blocks/CU.
// ---------------------------------------------------------------------------
__global__ __launch_bounds__(128) void k1_gemm(
    const float* __restrict__ E, const float* __restrict__ pos,
    const float* __restrict__ ppos, const float* __restrict__ W1,
    const float* __restrict__ b1, float* __restrict__ P, int KC)
{
    __shared__ float Es[8][192];

    const int tid = threadIdx.x;
    const int i0  = blockIdx.x * 8;
    const int kcc = blockIdx.y;
    const int k0  = kcc * KC;

    const int hg  = tid & 31;       // h-group: 4 consecutive h2 cols
    const int h0  = hg * 4;         // 0..127 (A: 0..63, B: 64..127)
    const int mat = h0 >> 6;
    const int hc  = h0 & 63;
    const int rp  = tid >> 5;       // 0..3 -> rows 2rp, 2rp+1
    const float* Wbase = W1 + (size_t)(mat * D + k0) * H + hc;

    f4 acc0 = {0.f, 0.f, 0.f, 0.f};
    f4 acc1 = {0.f, 0.f, 0.f, 0.f};

    for (int ks = 0; ks < KC; ks += 192) {
        if (ks) __syncthreads();
        // stage E[i0..i0+8)[k0+ks .. +192): 384 f4 -> 3 per thread
        for (int f = tid; f < 8 * 48; f += 128) {
            int row = f / 48, c = f - row * 48;
            *(f4*)&Es[row][c * 4] =
                *(const f4*)&E[(size_t)(i0 + row) * D + k0 + ks + c * 4];
        }
        __syncthreads();

        const float* Wc  = Wbase + (size_t)ks * H;
        const float* e0p = Es[2 * rp];
        const float* e1p = Es[2 * rp + 1];
        for (int kk = 0; kk < 192; kk += 8) {
#pragma unroll
            for (int u = 0; u < 8; ++u) {
                f4 w = *(const f4*)&Wc[(size_t)(kk + u) * H];
                float e0 = e0p[kk + u], e1 = e1p[kk + u];
                acc0 = __builtin_elementwise_fma((f4){e0, e0, e0, e0}, w, acc0);
                acc1 = __builtin_elementwise_fma((f4){e1, e1, e1, e1}, w, acc1);
            }
        }
    }

    if (kcc == 0) {
        const float* Ws = W1 + (size_t)2 * D * H + hc;
        f4 wp0 = *(const f4*)&Ws[0 * H];
        f4 wp1 = *(const f4*)&Ws[1 * H] + *(const f4*)&Ws[7 * H]; // vdiff fold
        f4 wp2 = *(const f4*)&Ws[2 * H];
        f4 wv0 = *(const f4*)&Ws[4 * H];
        f4 wv1 = *(const f4*)&Ws[5 * H];
        f4 wv2 = *(const f4*)&Ws[6 * H];
        f4 bb  = *(const f4*)&b1[hc];
#pragma unroll
        for (int r = 0; r < 2; ++r) {
            int i = i0 + 2 * rp + r;
            float px = pos[3 * i], py = pos[3 * i + 1], pz = pos[3 * i + 2];
            float vx = px - ppos[3 * i];
            float vy = py - ppos[3 * i + 1];
            float vz = pz - ppos[3 * i + 2];
            f4 g = px * wp0 + py * wp1 + pz * wp2 + vx * wv0 + vy * wv1 + vz * wv2;
            f4 add = (mat == 0) ? (bb - g) : g;
            if (r == 0) acc0 += add; else acc1 += add;
        }
    }

#pragma unroll
    for (int r = 0; r < 2; ++r) {
        int i = i0 + 2 * rp + r;
        f4 a = r ? acc1 : acc0;
#pragma unroll
        for (int c = 0; c < 4; ++c)
            P[(size_t)(kcc * 128 + h0 + c) * N + i] = a[c];
    }
}

// ---------------------------------------------------------------------------
// Kernel 2: 32x64 pair tile per block (1152 blocks, 128 threads), 4x4 pairs
// per thread: per h-iter only 2x ds_read_b128 + 2 broadcasts feed 112 FLOPs.
// ---------------------------------------------------------------------------
__global__ __launch_bounds__(128) void k2_main(
    const float* __restrict__ P, int nkc,
    const float* __restrict__ W1, const float* __restrict__ W2,
    const float* __restrict__ b2, const float* __restrict__ pos,
    const float* __restrict__ ppos, float* __restrict__ out)
{
    __shared__ float As[64][32];   // [h][i_local]
    __shared__ f4 Bs[64][16];      // [h][j_local/4]
    __shared__ float w3s[64];
    __shared__ f4 W2s[64];
    __shared__ float pis[32][3], vis[32][3], pjs[64][3], vjs[64][3];

    const int tid = threadIdx.x;
    const int i0 = blockIdx.y * 32;
    const int j0 = blockIdx.x * 64;

    // stage A tile: 64h x 32i = 512 f4 -> 4 per thread
#pragma unroll
    for (int g = 0; g < 4; ++g) {
        int f = g * 128 + tid;
        int h = f >> 3, c = f & 7;
        f4 s = {0.f, 0.f, 0.f, 0.f};
        for (int kc = 0; kc < nkc; ++kc)
            s += *(const f4*)&P[(size_t)(kc * 128 + h) * N + i0 + c * 4];
        *(f4*)&As[h][c * 4] = s;
    }
    // stage B tile: 64h x 64j = 1024 f4 -> 8 per thread
#pragma unroll
    for (int g = 0; g < 8; ++g) {
        int f = g * 128 + tid;
        int h = f >> 4, c = f & 15;
        f4 s = {0.f, 0.f, 0.f, 0.f};
        for (int kc = 0; kc < nkc; ++kc)
            s += *(const f4*)&P[(size_t)(kc * 128 + 64 + h) * N + j0 + c * 4];
        Bs[h][c] = s;
    }
    if (tid < 64) {
        w3s[tid] = W1[(size_t)(2 * D + 3) * H + tid];
        W2s[tid] = *(const f4*)&W2[tid * 4];
        int j = j0 + tid;
        float px = pos[3 * j], py = pos[3 * j + 1], pz = pos[3 * j + 2];
        pjs[tid][0] = px; pjs[tid][1] = py; pjs[tid][2] = pz;
        vjs[tid][0] = px - ppos[3 * j];
        vjs[tid][1] = py - ppos[3 * j + 1];
        vjs[tid][2] = pz - ppos[3 * j + 2];
    } else if (tid < 96) {
        int t = tid - 64;
        int i = i0 + t;
        float px = pos[3 * i], py = pos[3 * i + 1], pz = pos[3 * i + 2];
        pis[t][0] = px; pis[t][1] = py; pis[t][2] = pz;
        vis[t][0] = px - ppos[3 * i];
        vis[t][1] = py - ppos[3 * i + 1];
        vis[t][2] = pz - ppos[3 * i + 2];
    }
    __syncthreads();

    const int tx = tid & 15;   // j: tx*4 + 0..3
    const int ty = tid >> 4;   // i: ty*4 + 0..3  (ty in 0..7)

    // pair distances, numpy op order (threshold-sensitive)
    float dist[4][4];
    {
#pragma clang fp contract(off)
#pragma unroll
        for (int a = 0; a < 4; ++a) {
#pragma unroll
            for (int b = 0; b < 4; ++b) {
                int il = ty * 4 + a, jl = tx * 4 + b;
                float dx = pjs[jl][0] - pis[il][0];
                float dy = pjs[jl][1] - pis[il][1];
                float dz = pjs[jl][2] - pis[il][2];
                float s = dx * dx;
                s = s + dy * dy;
                s = s + dz * dz;
                dist[a][b] = sqrtf(s);
            }
        }
    }

    f4 acc[4][4];
#pragma unroll
    for (int a = 0; a < 4; ++a)
#pragma unroll
        for (int b = 0; b < 4; ++b)
            acc[a][b] = (f4){0.f, 0.f, 0.f, 0.f};

#pragma unroll 4
    for (int h = 0; h < 64; ++h) {
        f4 A4 = *(const f4*)&As[h][ty * 4];
        f4 B4 = Bs[h][tx];
        float w3h = w3s[h];
        f4 w2r = W2s[h];
#pragma unroll
        for (int a = 0; a < 4; ++a) {
#pragma unroll
            for (int b = 0; b < 4; ++b) {
                float hid = fmaf(dist[a][b], w3h, A4[a] + B4[b]);
                hid = fmaxf(hid, 0.f);
                acc[a][b] = __builtin_elementwise_fma(
                    (f4){hid, hid, hid, hid}, w2r, acc[a][b]);
            }
        }
    }

    const f4 B2v = *(const f4*)b2;

#pragma unroll
    for (int a = 0; a < 4; ++a) {
        int il = ty * 4 + a;
        int i = i0 + il;
        f4 rt4, cf4, vl4;
#pragma unroll
        for (int b = 0; b < 4; ++b) {
            int jl = tx * 4 + b;
            int j = j0 + jl;
            float dd = dist[a][b];
            float dy, closing;
            {
#pragma clang fp contract(off)
                float dx = pjs[jl][0] - pis[il][0];
                dy       = pjs[jl][1] - pis[il][1];
                float dz = pjs[jl][2] - pis[il][2];
                float rvx = vjs[jl][0] - vis[il][0];
                float rvy = vjs[jl][1] - vis[il][1];
                float rvz = vjs[jl][2] - vis[il][2];
                float dot = dx * rvx;
                dot = dot + dy * rvy;
                dot = dot + dz * rvz;
                closing = -dot / fmaxf(dd, 1e-6f);
            }
            f4 l = acc[a][b] + B2v;
            float mx = l.x; int bidx = 0;
            if (l.y > mx) { mx = l.y; bidx = 1; }
            if (l.z > mx) { mx = l.z; bidx = 2; }
            if (l.w > mx) { mx = l.w; bidx = 3; }
            float s = expf(l.x - mx);
            s += expf(l.y - mx);
            s += expf(l.z - mx);
            s += expf(l.w - mx);
            float conf = 1.0f / s;   // == max softmax prob

            bool near = dd < 0.25f;
            bool appr = !near && (closing > 0.05f);
            bool flee = !near && !appr && (closing < -0.05f);
            bool above = !near && !appr && !flee && (fabsf(dy) > 0.3f) && (dd < 0.5f);
            int rt = near ? 0 : appr ? 1 : flee ? 2 : above ? 3 : bidx;
            float co = near  ? fmaxf(conf, 0.8f)
                     : appr  ? fmaxf(conf, 0.6f)
                     : flee  ? fmaxf(conf, 0.6f)
                     : above ? fmaxf(conf, 0.5f)
                             : conf;
            float vd = ((j > i) && (co > 0.3f)) ? 1.0f : 0.0f;
            rt4[b] = (float)rt;
            cf4[b] = co;
            vl4[b] = vd;
        }
        int col = j0 + tx * 4;
        *(f4*)&out[(size_t)i * N + col]                  = rt4;
        *(f4*)&out[(size_t)NN + (size_t)i * N + col]     = cf4;
        *(f4*)&out[(size_t)2 * NN + (size_t)i * N + col] = vl4;
    }
}

extern "C" void kernel_launch(void* const* d_in, const int* in_sizes, int n_in,
                              void* d_out, int out_size, void* d_ws, size_t ws_size,
                              hipStream_t stream)
{
    const float* E    = (const float*)d_in[0];   // N x 768
    const float* pos  = (const float*)d_in[1];   // N x 3
    const float* ppos = (const float*)d_in[2];   // N x 3
    const float* W1   = (const float*)d_in[3];   // 1544 x 64
    const float* b1   = (const float*)d_in[4];   // 64
    const float* W2   = (const float*)d_in[5];   // 64 x 4
    const float* b2   = (const float*)d_in[6];   // 4
    float* out = (float*)d_out;
    float* P   = (float*)d_ws;

    int nkc = (ws_size >= (size_t)4 * 128 * N * 4) ? 4 : 1;
    int KC  = D / nkc;

    dim3 g1(N / 8, nkc);
    k1_gemm<<<g1, 128, 0, stream>>>(E, pos, ppos, W1, b1, P, KC);

    dim3 g2(N / 64, N / 32);
    k2_main<<<g2, 128, 0, stream>>>(P, nkc, W1, W2, b2, pos, ppos, out);
}

// Round 4
// 123.429 us; speedup vs baseline: 1.2177x; 1.2177x over previous
//
#include <hip/hip_runtime.h>

typedef float f4 __attribute__((ext_vector_type(4)));
typedef float f2 __attribute__((ext_vector_type(2)));

#define N 1536
#define D 768
#define H 64
#define NN (N * N)

// ---------------------------------------------------------------------------
// Kernel 1a: split-K GEMM partials (UNCHANGED from R3 - proven numerics).
// A[i,h] = (E @ W1a)[i,h] + b1[h] - p_i.Wp[h] - v_i.Wv[h]
// B[j,h] = (E @ W1b)[j,h]        + p_j.Wp[h] + v_j.Wv[h]
// P[kc][h2][i], h2 in [0,128): 0..63 = A, 64..127 = B.
// ---------------------------------------------------------------------------
__global__ __launch_bounds__(128) void k1_gemm(
    const float* __restrict__ E, const float* __restrict__ pos,
    const float* __restrict__ ppos, const float* __restrict__ W1,
    const float* __restrict__ b1, float* __restrict__ P, int KC)
{
    __shared__ float Es[8][192];

    const int tid = threadIdx.x;
    const int i0  = blockIdx.x * 8;
    const int kcc = blockIdx.y;
    const int k0  = kcc * KC;

    const int hg  = tid & 31;
    const int h0  = hg * 4;
    const int mat = h0 >> 6;
    const int hc  = h0 & 63;
    const int rp  = tid >> 5;
    const float* Wbase = W1 + (size_t)(mat * D + k0) * H + hc;

    f4 acc0 = {0.f, 0.f, 0.f, 0.f};
    f4 acc1 = {0.f, 0.f, 0.f, 0.f};

    for (int ks = 0; ks < KC; ks += 192) {
        if (ks) __syncthreads();
        for (int f = tid; f < 8 * 48; f += 128) {
            int row = f / 48, c = f - row * 48;
            *(f4*)&Es[row][c * 4] =
                *(const f4*)&E[(size_t)(i0 + row) * D + k0 + ks + c * 4];
        }
        __syncthreads();

        const float* Wc  = Wbase + (size_t)ks * H;
        const float* e0p = Es[2 * rp];
        const float* e1p = Es[2 * rp + 1];
        for (int kk = 0; kk < 192; kk += 8) {
#pragma unroll
            for (int u = 0; u < 8; ++u) {
                f4 w = *(const f4*)&Wc[(size_t)(kk + u) * H];
                float e0 = e0p[kk + u], e1 = e1p[kk + u];
                acc0 = __builtin_elementwise_fma((f4){e0, e0, e0, e0}, w, acc0);
                acc1 = __builtin_elementwise_fma((f4){e1, e1, e1, e1}, w, acc1);
            }
        }
    }

    if (kcc == 0) {
        const float* Ws = W1 + (size_t)2 * D * H + hc;
        f4 wp0 = *(const f4*)&Ws[0 * H];
        f4 wp1 = *(const f4*)&Ws[1 * H] + *(const f4*)&Ws[7 * H]; // vdiff fold
        f4 wp2 = *(const f4*)&Ws[2 * H];
        f4 wv0 = *(const f4*)&Ws[4 * H];
        f4 wv1 = *(const f4*)&Ws[5 * H];
        f4 wv2 = *(const f4*)&Ws[6 * H];
        f4 bb  = *(const f4*)&b1[hc];
#pragma unroll
        for (int r = 0; r < 2; ++r) {
            int i = i0 + 2 * rp + r;
            float px = pos[3 * i], py = pos[3 * i + 1], pz = pos[3 * i + 2];
            float vx = px - ppos[3 * i];
            float vy = py - ppos[3 * i + 1];
            float vz = pz - ppos[3 * i + 2];
            f4 g = px * wp0 + py * wp1 + pz * wp2 + vx * wv0 + vy * wv1 + vz * wv2;
            f4 add = (mat == 0) ? (bb - g) : g;
            if (r == 0) acc0 += add; else acc1 += add;
        }
    }

#pragma unroll
    for (int r = 0; r < 2; ++r) {
        int i = i0 + 2 * rp + r;
        f4 a = r ? acc1 : acc0;
#pragma unroll
        for (int c = 0; c < 4; ++c)
            P[(size_t)(kcc * 128 + h0 + c) * N + i] = a[c];
    }
}

// ---------------------------------------------------------------------------
// Kernel 1b: reduce split-K partials once (same kc order as R2's k2 staging
// -> bit-identical A/B values). AB[h2][i] final.
// ---------------------------------------------------------------------------
__global__ __launch_bounds__(256) void k1b_reduce(
    const float* __restrict__ P, float* __restrict__ AB, int nkc)
{
    int idx = blockIdx.x * 256 + threadIdx.x;   // f4 index, 49152 total
    f4 s = {0.f, 0.f, 0.f, 0.f};
    for (int kc = 0; kc < nkc; ++kc)
        s += *(const f4*)&P[(size_t)kc * 128 * N + (size_t)idx * 4];
    *(f4*)&AB[(size_t)idx * 4] = s;
}

// ---------------------------------------------------------------------------
// Kernel 2: 32x32 pair tile, 128 threads, 2304 blocks = 9 blocks/CU exact.
// LDS 16.4KB (union overlay) -> all 9 co-resident, 4.5 waves/SIMD.
// Inner loop: 2 DS reads per h (A b128, B b64); w3/W2 via uniform s_load.
// Geometry precomputed to registers; numerics bit-identical to R2/R3.
// ---------------------------------------------------------------------------
__global__ __launch_bounds__(128) void k2_main(
    const float* __restrict__ AB, const float* __restrict__ W1,
    const float* __restrict__ W2, const float* __restrict__ b2,
    const float* __restrict__ pos, const float* __restrict__ ppos,
    float* __restrict__ out)
{
    __shared__ union SMem {
        struct { float pi[32][3], vi[32][3], pj[32][3], vj[32][3]; } g;
        struct { float As[64][32], Bs[64][32]; } t;
    } sm;

    const int tid = threadIdx.x;
    const int i0 = blockIdx.y * 32;
    const int j0 = blockIdx.x * 32;

    // ---- phase 1: stage pos/vel, compute per-pair geometry into registers
    if (tid < 32) {
        int i = i0 + tid;
        float px = pos[3 * i], py = pos[3 * i + 1], pz = pos[3 * i + 2];
        sm.g.pi[tid][0] = px; sm.g.pi[tid][1] = py; sm.g.pi[tid][2] = pz;
        sm.g.vi[tid][0] = px - ppos[3 * i];
        sm.g.vi[tid][1] = py - ppos[3 * i + 1];
        sm.g.vi[tid][2] = pz - ppos[3 * i + 2];
    } else if (tid < 64) {
        int t = tid - 32;
        int j = j0 + t;
        float px = pos[3 * j], py = pos[3 * j + 1], pz = pos[3 * j + 2];
        sm.g.pj[t][0] = px; sm.g.pj[t][1] = py; sm.g.pj[t][2] = pz;
        sm.g.vj[t][0] = px - ppos[3 * j];
        sm.g.vj[t][1] = py - ppos[3 * j + 1];
        sm.g.vj[t][2] = pz - ppos[3 * j + 2];
    }
    __syncthreads();

    const int tx = tid & 15;   // j: tx*2 + 0..1
    const int ty = tid >> 4;   // i: ty*4 + 0..3

    f2 dd[4], dyv[4], clv[4];
    {
#pragma clang fp contract(off)
#pragma unroll
        for (int a = 0; a < 4; ++a) {
#pragma unroll
            for (int b = 0; b < 2; ++b) {
                int il = ty * 4 + a, jl = tx * 2 + b;
                float dx = sm.g.pj[jl][0] - sm.g.pi[il][0];
                float dy = sm.g.pj[jl][1] - sm.g.pi[il][1];
                float dz = sm.g.pj[jl][2] - sm.g.pi[il][2];
                float s = dx * dx;
                s = s + dy * dy;
                s = s + dz * dz;
                float d = sqrtf(s);
                float rvx = sm.g.vj[jl][0] - sm.g.vi[il][0];
                float rvy = sm.g.vj[jl][1] - sm.g.vi[il][1];
                float rvz = sm.g.vj[jl][2] - sm.g.vi[il][2];
                float dot = dx * rvx;
                dot = dot + dy * rvy;
                dot = dot + dz * rvz;
                float cl = -dot / fmaxf(d, 1e-6f);
                dd[a][b] = d; dyv[a][b] = dy; clv[a][b] = cl;
            }
        }
    }
    __syncthreads();   // all geometry reads done before overlay reuse

    // ---- phase 2: stage A/B tiles (single pre-reduced source)
#pragma unroll
    for (int g = 0; g < 4; ++g) {
        int f = g * 128 + tid;
        int h = f >> 3, c = f & 7;
        *(f4*)&sm.t.As[h][c * 4] = *(const f4*)&AB[(size_t)h * N + i0 + c * 4];
        *(f4*)&sm.t.Bs[h][c * 4] = *(const f4*)&AB[(size_t)(64 + h) * N + j0 + c * 4];
    }
    __syncthreads();

    // ---- phase 3: MLP inner loop
    f2 acc[4][4];
#pragma unroll
    for (int a = 0; a < 4; ++a)
#pragma unroll
        for (int l = 0; l < 4; ++l)
            acc[a][l] = (f2){0.f, 0.f};

    const float* w3p = W1 + (size_t)(2 * D + 3) * H;   // w3p[h], uniform

#pragma unroll 4
    for (int h = 0; h < 64; ++h) {
        f4 A4 = *(const f4*)&sm.t.As[h][ty * 4];
        f2 B2 = *(const f2*)&sm.t.Bs[h][tx * 2];
        float w3h = w3p[h];
        f4 w2r = *(const f4*)&W2[h * 4];
        f2 w3v = (f2){w3h, w3h};
#pragma unroll
        for (int a = 0; a < 4; ++a) {
            f2 pre = (f2){A4[a], A4[a]} + B2;
            f2 hid = __builtin_elementwise_fma(dd[a], w3v, pre);
            hid = __builtin_elementwise_max(hid, (f2){0.f, 0.f});
            acc[a][0] = __builtin_elementwise_fma(hid, (f2){w2r.x, w2r.x}, acc[a][0]);
            acc[a][1] = __builtin_elementwise_fma(hid, (f2){w2r.y, w2r.y}, acc[a][1]);
            acc[a][2] = __builtin_elementwise_fma(hid, (f2){w2r.z, w2r.z}, acc[a][2]);
            acc[a][3] = __builtin_elementwise_fma(hid, (f2){w2r.w, w2r.w}, acc[a][3]);
        }
    }

    // ---- phase 4: epilogue (pure registers)
    const f4 B2v = *(const f4*)b2;

#pragma unroll
    for (int a = 0; a < 4; ++a) {
        int i = i0 + ty * 4 + a;
        f2 rt2, cf2, vl2;
#pragma unroll
        for (int b = 0; b < 2; ++b) {
            int j = j0 + tx * 2 + b;
            float l0 = acc[a][0][b] + B2v.x;
            float l1 = acc[a][1][b] + B2v.y;
            float l2 = acc[a][2][b] + B2v.z;
            float l3 = acc[a][3][b] + B2v.w;
            float mx = l0; int bidx = 0;
            if (l1 > mx) { mx = l1; bidx = 1; }
            if (l2 > mx) { mx = l2; bidx = 2; }
            if (l3 > mx) { mx = l3; bidx = 3; }
            float s = expf(l0 - mx);
            s += expf(l1 - mx);
            s += expf(l2 - mx);
            s += expf(l3 - mx);
            float conf = 1.0f / s;   // == max softmax prob

            float d  = dd[a][b];
            float dy = dyv[a][b];
            float cl = clv[a][b];
            bool near = d < 0.25f;
            bool appr = !near && (cl > 0.05f);
            bool flee = !near && !appr && (cl < -0.05f);
            bool above = !near && !appr && !flee && (fabsf(dy) > 0.3f) && (d < 0.5f);
            int rt = near ? 0 : appr ? 1 : flee ? 2 : above ? 3 : bidx;
            float co = near  ? fmaxf(conf, 0.8f)
                     : appr  ? fmaxf(conf, 0.6f)
                     : flee  ? fmaxf(conf, 0.6f)
                     : above ? fmaxf(conf, 0.5f)
                             : conf;
            float vd = ((j > i) && (co > 0.3f)) ? 1.0f : 0.0f;
            rt2[b] = (float)rt;
            cf2[b] = co;
            vl2[b] = vd;
        }
        int col = j0 + tx * 2;
        *(f2*)&out[(size_t)i * N + col]                  = rt2;
        *(f2*)&out[(size_t)NN + (size_t)i * N + col]     = cf2;
        *(f2*)&out[(size_t)2 * NN + (size_t)i * N + col] = vl2;
    }
}

extern "C" void kernel_launch(void* const* d_in, const int* in_sizes, int n_in,
                              void* d_out, int out_size, void* d_ws, size_t ws_size,
                              hipStream_t stream)
{
    const float* E    = (const float*)d_in[0];   // N x 768
    const float* pos  = (const float*)d_in[1];   // N x 3
    const float* ppos = (const float*)d_in[2];   // N x 3
    const float* W1   = (const float*)d_in[3];   // 1544 x 64
    const float* b1   = (const float*)d_in[4];   // 64
    const float* W2   = (const float*)d_in[5];   // 64 x 4
    const float* b2   = (const float*)d_in[6];   // 4
    float* out = (float*)d_out;
    float* P   = (float*)d_ws;

    const size_t part_sz = (size_t)4 * 128 * N;            // floats, nkc=4 partials
    const size_t ab_sz   = (size_t)128 * N;                // floats, final AB
    int nkc = (ws_size >= (part_sz + ab_sz) * sizeof(float)) ? 4 : 1;
    int KC  = D / nkc;

    dim3 g1(N / 8, nkc);
    k1_gemm<<<g1, 128, 0, stream>>>(E, pos, ppos, W1, b1, P, KC);

    const float* AB;
    if (nkc > 1) {
        float* ABw = P + part_sz;
        k1b_reduce<<<(128 * N / 4) / 256, 256, 0, stream>>>(P, ABw, nkc);
        AB = ABw;
    } else {
        AB = P;   // single partial already includes bias/geometry
    }

    dim3 g2(N / 32, N / 32);
    k2_main<<<g2, 128, 0, stream>>>(AB, W1, W2, b2, pos, ppos, out);
}